// Round 7
// baseline (209.857 us; speedup 1.0000x reference)
//
#include <hip/hip_runtime.h>

// YOLO v1 loss, two-kernel fused reduction.
// input_: [B, 30, 7, 7] fp32   (channel-major per image, 1470 floats/batch)
// target: [B, 7, 7, 30] fp32   (cell-major, 30 contiguous per cell)
// out   : [1] fp32 scalar loss
//
// Round-7: R6 showed VGPR=40 with 45 asm loads => compiler spill-consumed
// each load (wait per load, re-serialized). Fix:
//  (1) __launch_bounds__(256,4): allow 128 VGPRs so ~66 live dwords need no
//      spill (R3-R6 all got occupancy-capped to <=64 VGPR).
//  (2) loads + s_waitcnt vmcnt(0) in ONE asm block (2 blocks x ~23 loads):
//      nothing can be scheduled between issue and wait; each block's loads
//      are all concurrently in flight; outputs valid at asm exit.

typedef float f32x2 __attribute__((ext_vector_type(2)));

#define CELLF   64.0f
#define IMGF    448.0f
#define EPSF    1e-6f
#define LAMBDA_COORD 5.0f
#define LAMBDA_NOOBJ 0.5f

#define TPB 256

__global__ __launch_bounds__(TPB, 4) void yolo_main(
    const float* __restrict__ input,
    const float* __restrict__ target,
    float* __restrict__ partial,
    int ncells)
{
    const int tid = threadIdx.x;
    const int n   = blockIdx.x * TPB + tid;

    float lv = 0.0f;
    if (n < ncells) {
        const int b    = n / 49;
        const int cell = n - b * 49;
        const int row  = cell / 7;
        const int col  = cell - row * 7;

        // input channel c at byte offset c*196 - 2744 from shifted base
        // (offsets span [-2744, 2940], within 13-bit signed immediate)
        const char* xa = (const char*)(input + (size_t)b * 1470 + cell) + 2744;
        const char* ta = (const char*)(target + (size_t)n * 30);   // 8B-aligned

        float x[30];
        f32x2 tv[15];

        // ---- block A: x[0..14], t rows 0..7; issue 23 loads, wait once ----
        asm volatile(
            "global_load_dword %[a0],  %[xa], off offset:-2744\n\t"
            "global_load_dword %[a1],  %[xa], off offset:-2548\n\t"
            "global_load_dword %[a2],  %[xa], off offset:-2352\n\t"
            "global_load_dword %[a3],  %[xa], off offset:-2156\n\t"
            "global_load_dword %[a4],  %[xa], off offset:-1960\n\t"
            "global_load_dword %[a5],  %[xa], off offset:-1764\n\t"
            "global_load_dword %[a6],  %[xa], off offset:-1568\n\t"
            "global_load_dword %[a7],  %[xa], off offset:-1372\n\t"
            "global_load_dword %[a8],  %[xa], off offset:-1176\n\t"
            "global_load_dword %[a9],  %[xa], off offset:-980\n\t"
            "global_load_dword %[a10], %[xa], off offset:-784\n\t"
            "global_load_dword %[a11], %[xa], off offset:-588\n\t"
            "global_load_dword %[a12], %[xa], off offset:-392\n\t"
            "global_load_dword %[a13], %[xa], off offset:-196\n\t"
            "global_load_dword %[a14], %[xa], off offset:0\n\t"
            "global_load_dwordx2 %[b0], %[ta], off offset:0\n\t"
            "global_load_dwordx2 %[b1], %[ta], off offset:8\n\t"
            "global_load_dwordx2 %[b2], %[ta], off offset:16\n\t"
            "global_load_dwordx2 %[b3], %[ta], off offset:24\n\t"
            "global_load_dwordx2 %[b4], %[ta], off offset:32\n\t"
            "global_load_dwordx2 %[b5], %[ta], off offset:40\n\t"
            "global_load_dwordx2 %[b6], %[ta], off offset:48\n\t"
            "global_load_dwordx2 %[b7], %[ta], off offset:56\n\t"
            "s_waitcnt vmcnt(0)"
            : [a0]"=&v"(x[0]),  [a1]"=&v"(x[1]),  [a2]"=&v"(x[2]),
              [a3]"=&v"(x[3]),  [a4]"=&v"(x[4]),  [a5]"=&v"(x[5]),
              [a6]"=&v"(x[6]),  [a7]"=&v"(x[7]),  [a8]"=&v"(x[8]),
              [a9]"=&v"(x[9]),  [a10]"=&v"(x[10]), [a11]"=&v"(x[11]),
              [a12]"=&v"(x[12]), [a13]"=&v"(x[13]), [a14]"=&v"(x[14]),
              [b0]"=&v"(tv[0]), [b1]"=&v"(tv[1]), [b2]"=&v"(tv[2]),
              [b3]"=&v"(tv[3]), [b4]"=&v"(tv[4]), [b5]"=&v"(tv[5]),
              [b6]"=&v"(tv[6]), [b7]"=&v"(tv[7])
            : [xa]"v"(xa), [ta]"v"(ta)
            : "memory");
        __builtin_amdgcn_sched_barrier(0);

        // ---- block B: x[15..29], t rows 8..14 ----
        asm volatile(
            "global_load_dword %[a15], %[xa], off offset:196\n\t"
            "global_load_dword %[a16], %[xa], off offset:392\n\t"
            "global_load_dword %[a17], %[xa], off offset:588\n\t"
            "global_load_dword %[a18], %[xa], off offset:784\n\t"
            "global_load_dword %[a19], %[xa], off offset:980\n\t"
            "global_load_dword %[a20], %[xa], off offset:1176\n\t"
            "global_load_dword %[a21], %[xa], off offset:1372\n\t"
            "global_load_dword %[a22], %[xa], off offset:1568\n\t"
            "global_load_dword %[a23], %[xa], off offset:1764\n\t"
            "global_load_dword %[a24], %[xa], off offset:1960\n\t"
            "global_load_dword %[a25], %[xa], off offset:2156\n\t"
            "global_load_dword %[a26], %[xa], off offset:2352\n\t"
            "global_load_dword %[a27], %[xa], off offset:2548\n\t"
            "global_load_dword %[a28], %[xa], off offset:2744\n\t"
            "global_load_dword %[a29], %[xa], off offset:2940\n\t"
            "global_load_dwordx2 %[b8],  %[ta], off offset:64\n\t"
            "global_load_dwordx2 %[b9],  %[ta], off offset:72\n\t"
            "global_load_dwordx2 %[b10], %[ta], off offset:80\n\t"
            "global_load_dwordx2 %[b11], %[ta], off offset:88\n\t"
            "global_load_dwordx2 %[b12], %[ta], off offset:96\n\t"
            "global_load_dwordx2 %[b13], %[ta], off offset:104\n\t"
            "global_load_dwordx2 %[b14], %[ta], off offset:112\n\t"
            "s_waitcnt vmcnt(0)"
            : [a15]"=&v"(x[15]), [a16]"=&v"(x[16]), [a17]"=&v"(x[17]),
              [a18]"=&v"(x[18]), [a19]"=&v"(x[19]), [a20]"=&v"(x[20]),
              [a21]"=&v"(x[21]), [a22]"=&v"(x[22]), [a23]"=&v"(x[23]),
              [a24]"=&v"(x[24]), [a25]"=&v"(x[25]), [a26]"=&v"(x[26]),
              [a27]"=&v"(x[27]), [a28]"=&v"(x[28]), [a29]"=&v"(x[29]),
              [b8]"=&v"(tv[8]),  [b9]"=&v"(tv[9]),  [b10]"=&v"(tv[10]),
              [b11]"=&v"(tv[11]), [b12]"=&v"(tv[12]), [b13]"=&v"(tv[13]),
              [b14]"=&v"(tv[14])
            : [xa]"v"(xa), [ta]"v"(ta)
            : "memory");
        __builtin_amdgcn_sched_barrier(0);

        float t[30];
        #pragma unroll
        for (int j = 0; j < 15; ++j) {
            t[2 * j]     = tv[j].x;
            t[2 * j + 1] = tv[j].y;
        }

        const float colf = (float)col * CELLF;
        const float rowf = (float)row * CELLF;

        float iou[2];
        #pragma unroll
        for (int k = 0; k < 2; ++k) {
            const int o = 5 * k;
            float pcx = x[o + 0] * CELLF + colf;
            float pcy = x[o + 1] * CELLF + rowf;
            float pw  = x[o + 2] * IMGF;
            float ph  = x[o + 3] * IMGF;
            float px1 = fminf(fmaxf(pcx - 0.5f * pw, 0.0f), IMGF);
            float py1 = fminf(fmaxf(pcy - 0.5f * ph, 0.0f), IMGF);
            float px2 = fminf(fmaxf(pcx + 0.5f * pw, 0.0f), IMGF);
            float py2 = fminf(fmaxf(pcy + 0.5f * ph, 0.0f), IMGF);

            float tcx = t[o + 0] * CELLF + colf;
            float tcy = t[o + 1] * CELLF + rowf;
            float tw  = t[o + 2] * IMGF;
            float th  = t[o + 3] * IMGF;
            float tx1 = fminf(fmaxf(tcx - 0.5f * tw, 0.0f), IMGF);
            float ty1 = fminf(fmaxf(tcy - 0.5f * th, 0.0f), IMGF);
            float tx2 = fminf(fmaxf(tcx + 0.5f * tw, 0.0f), IMGF);
            float ty2 = fminf(fmaxf(tcy + 0.5f * th, 0.0f), IMGF);

            float iw = fmaxf(fminf(px2, tx2) - fmaxf(px1, tx1), EPSF);
            float ih = fmaxf(fminf(py2, ty2) - fmaxf(py1, ty1), EPSF);
            float inter = iw * ih;
            float area  = (px2 - px1) * (py2 - py1) + (tx2 - tx1) * (ty2 - ty1);
            iou[k] = inter / (area - inter);
        }

        const bool  m      = iou[0] < iou[1];
        const float iouSel = m ? iou[1] : iou[0];
        const float has_obj = (t[4] == 1.0f) ? 1.0f : 0.0f;
        const float no_obj  = 1.0f - has_obj;

        const float s0 = m ? x[5] : x[0];
        const float s1 = m ? x[6] : x[1];
        const float s2 = m ? x[7] : x[2];
        const float s3 = m ? x[8] : x[3];
        const float s4 = m ? x[9] : x[4];

        float d0 = s0 - t[0], d1 = s1 - t[1];
        float coord_e = d0 * d0 + d1 * d1;

        float e2 = sqrtf(s2) - sqrtf(t[2]);
        float e3 = sqrtf(s3) - sqrtf(t[3]);
        float size_e = e2 * e2 + e3 * e3;

        float dc = s4 - iouSel;
        float conf_e = dc * dc;

        float cls_e = 0.0f;
        #pragma unroll
        for (int c = 10; c < 30; ++c) {
            float d = x[c] - t[c];
            cls_e += d * d;
        }

        float noobj_e = x[4] * x[4] + x[9] * x[9];

        lv = has_obj * (LAMBDA_COORD * coord_e + LAMBDA_COORD * size_e + conf_e + cls_e)
           + LAMBDA_NOOBJ * no_obj * noobj_e;
    }

    // ---- reduce: wave shuffle, then cross-wave via LDS ----
    #pragma unroll
    for (int off = 32; off > 0; off >>= 1)
        lv += __shfl_down(lv, off, 64);

    __shared__ float s_part[TPB / 64];
    if ((tid & 63) == 0) s_part[tid >> 6] = lv;
    __syncthreads();

    if (tid == 0) {
        float tot = 0.0f;
        #pragma unroll
        for (int w = 0; w < TPB / 64; ++w) tot += s_part[w];
        partial[blockIdx.x] = tot;
    }
}

__global__ __launch_bounds__(256) void yolo_reduce(
    const float* __restrict__ partial, int nparts,
    float* __restrict__ out, float inv_b)
{
    const int tid = threadIdx.x;
    float v = 0.0f;
    for (int i = tid; i < nparts; i += 256) v += partial[i];

    #pragma unroll
    for (int off = 32; off > 0; off >>= 1)
        v += __shfl_down(v, off, 64);

    __shared__ float s_part[4];
    if ((tid & 63) == 0) s_part[tid >> 6] = v;
    __syncthreads();

    if (tid == 0)
        out[0] = (s_part[0] + s_part[1] + s_part[2] + s_part[3]) * inv_b;
}

extern "C" void kernel_launch(void* const* d_in, const int* in_sizes, int n_in,
                              void* d_out, int out_size, void* d_ws, size_t ws_size,
                              hipStream_t stream) {
    const float* input  = (const float*)d_in[0];
    const float* target = (const float*)d_in[1];
    float* out = (float*)d_out;
    float* partial = (float*)d_ws;

    const int B = in_sizes[0] / (30 * 49);         // 16384
    const int ncells = B * 49;                     // 802816
    const int nblocks = (ncells + TPB - 1) / TPB;  // 3136

    yolo_main<<<nblocks, TPB, 0, stream>>>(input, target, partial, ncells);
    yolo_reduce<<<1, 256, 0, stream>>>(partial, nblocks, out, 1.0f / (float)B);
}